// Round 2
// baseline (3036.383 us; speedup 1.0000x reference)
//
#include <hip/hip_runtime.h>
#include <hip/hip_bf16.h>

// Shapes (fixed for this problem)
#define B_   16
#define C_   320
#define HW_  1024
#define CO_  256    // conv_out channels
#define NH_  4
#define DKH_ 160
#define QKVC 1344   // 2*640 + 64

using bf16x8 = __attribute__((ext_vector_type(8))) __bf16;
using f32x4  = __attribute__((ext_vector_type(4))) float;

static __device__ __forceinline__ bf16x8 bzero8() {
  bf16x8 r;
#pragma unroll
  for (int j = 0; j < 8; ++j) r[j] = (__bf16)0.0f;
  return r;
}

// ---------------------------------------------------------------------------
// Weight transform: w[co][ci][kh][kw] (fp32) -> wt[tap][co][ci] (bf16)
// ---------------------------------------------------------------------------
__global__ void transform_w(const float* __restrict__ w, __bf16* __restrict__ wt,
                            int total, int Cout) {
  int idx = blockIdx.x * 256 + threadIdx.x;
  if (idx >= total) return;
  int ci = idx % C_;
  int rest = idx / C_;
  int co = rest % Cout;
  int tap = rest / Cout;
  wt[idx] = (__bf16)w[(co * C_ + ci) * 9 + tap];
}

// ---------------------------------------------------------------------------
// BN + ReLU + NCHW->NHWC transpose.  x:[B][320][1024] -> y:[B][1024][320] bf16
// ---------------------------------------------------------------------------
template <typename TI>
__global__ __launch_bounds__(256)
void bn_relu_t(const TI* __restrict__ x, const float* __restrict__ g,
               const float* __restrict__ bb, const float* __restrict__ m,
               const float* __restrict__ v, __bf16* __restrict__ y) {
  __shared__ __bf16 tile[32][33];
  int b = blockIdx.z, c0 = blockIdx.y * 32, p0 = blockIdx.x * 32;
#pragma unroll
  for (int i = 0; i < 4; ++i) {
    int cl = threadIdx.y + i * 8;
    int c = c0 + cl;
    int p = p0 + threadIdx.x;
    float scale = g[c] * rsqrtf(v[c] + 1e-5f);
    float val = ((float)x[((size_t)b * C_ + c) * HW_ + p] - m[c]) * scale + bb[c];
    tile[cl][threadIdx.x] = (__bf16)fmaxf(val, 0.0f);
  }
  __syncthreads();
#pragma unroll
  for (int i = 0; i < 4; ++i) {
    int pl = threadIdx.y + i * 8;
    int p = p0 + pl;
    int c = c0 + threadIdx.x;
    y[((size_t)b * HW_ + p) * C_ + c] = tile[threadIdx.x][pl];
  }
}

// ---------------------------------------------------------------------------
// Implicit-GEMM 3x3 conv (pad=1) via MFMA 16x16x32 bf16.
// y: [B][1024][320] NHWC bf16.  wt: [9][Cout][320] bf16.
// Block: 256 threads / 4 waves, 64co x 64p per block, each wave 32co x 32p.
// mode 0: out NCHW [B][320][1024] channels [0,256) (+resid)
// mode 1: qkv scatter into qt/kt (p-major, q scaled) and vt (NCHW)
// ---------------------------------------------------------------------------
template <typename TO>
__global__ __launch_bounds__(256)
void conv3x3_mfma(const __bf16* __restrict__ y, const __bf16* __restrict__ wt,
                  const float* __restrict__ bias, int Cout, int mode,
                  TO* __restrict__ out, const float* __restrict__ resid,
                  __bf16* __restrict__ qt, __bf16* __restrict__ kt,
                  __bf16* __restrict__ vt) {
  int tid = threadIdx.x;
  int lane = tid & 63, wv = tid >> 6;
  int lr = lane & 15, lg = lane >> 4;
  int b = blockIdx.z;
  int co_w = blockIdx.y * 64 + (wv >> 1) * 32;
  int p_w  = blockIdx.x * 64 + (wv & 1) * 32;

  f32x4 zz = {0.f, 0.f, 0.f, 0.f};
  f32x4 acc[2][2];
#pragma unroll
  for (int mt = 0; mt < 2; ++mt)
#pragma unroll
    for (int nt = 0; nt < 2; ++nt) acc[mt][nt] = zz;

  int p_n[2], h0[2], w0[2];
#pragma unroll
  for (int nt = 0; nt < 2; ++nt) {
    int p = p_w + nt * 16 + lr;
    p_n[nt] = p; h0[nt] = p >> 5; w0[nt] = p & 31;
  }

  for (int tap = 0; tap < 9; ++tap) {
    int dh = tap / 3 - 1, dw = tap % 3 - 1;
    const __bf16* wbase = wt + ((size_t)tap * Cout + co_w) * C_;
    for (int cb = 0; cb < 10; ++cb) {
      int ci0 = cb * 32;
      bf16x8 af[2], bf[2];
#pragma unroll
      for (int mt = 0; mt < 2; ++mt)
        af[mt] = *(const bf16x8*)(wbase + (size_t)(mt * 16 + lr) * C_ + ci0 + lg * 8);
#pragma unroll
      for (int nt = 0; nt < 2; ++nt) {
        int hh = h0[nt] + dh, ww = w0[nt] + dw;
        if ((unsigned)hh < 32u && (unsigned)ww < 32u)
          bf[nt] = *(const bf16x8*)(y + ((size_t)(b * 32 + hh) * 32 + ww) * C_ + ci0 + lg * 8);
        else
          bf[nt] = bzero8();
      }
#pragma unroll
      for (int mt = 0; mt < 2; ++mt)
#pragma unroll
        for (int nt = 0; nt < 2; ++nt)
          acc[mt][nt] = __builtin_amdgcn_mfma_f32_16x16x32_bf16(af[mt], bf[nt], acc[mt][nt], 0, 0, 0);
    }
  }

  const float scaleq = 0.07905694150420949f; // 160^-0.5
#pragma unroll
  for (int mt = 0; mt < 2; ++mt) {
#pragma unroll
    for (int nt = 0; nt < 2; ++nt) {
#pragma unroll
      for (int r = 0; r < 4; ++r) {
        int co = co_w + mt * 16 + lg * 4 + r;
        int p = p_n[nt];
        float val = acc[mt][nt][r] + bias[co];
        if (mode == 0) {
          size_t o = ((size_t)b * C_ + co) * HW_ + p;
          if (resid) val += resid[o];
          out[o] = (TO)val;
        } else {
          if (co < 640) {
            int n = co / DKH_, d = co % DKH_;
            qt[(((size_t)b * NH_ + n) * HW_ + p) * DKH_ + d] = (__bf16)(val * scaleq);
          } else if (co < 1280) {
            int c2 = co - 640;
            int n = c2 / DKH_, d = c2 % DKH_;
            kt[(((size_t)b * NH_ + n) * HW_ + p) * DKH_ + d] = (__bf16)val;
          } else {
            int c3 = co - 1280;
            vt[((size_t)b * 64 + c3) * HW_ + p] = (__bf16)val;
          }
        }
      }
    }
  }
}

// ---------------------------------------------------------------------------
// Fused attention per (b, head, 16-query block).
// logits = q.k + q.rel_w[y'-y+31] + q.rel_h[x'-x+31]; softmax; P@V; scatter
// per the reference's raw reshape (b,NH,HW,dvh)->(b,64,H,W).
// 256 threads / 4 waves; wave w owns keys [w*256, w*256+256).
// ---------------------------------------------------------------------------
__global__ __launch_bounds__(256)
void attn_kernel(const __bf16* __restrict__ qt, const __bf16* __restrict__ kt,
                 const __bf16* __restrict__ vt, const float* __restrict__ relw,
                 const float* __restrict__ relh, __bf16* __restrict__ attn_out) {
  __shared__ __align__(16) __bf16 q_lds[16][168];   // pad 8 bf16
  __shared__ float rw[16][32];
  __shared__ float rh[16][32];
  __shared__ __align__(16) __bf16 p_lds[4][16][264]; // per-wave P, pad 8
  __shared__ float smax[16][4];
  __shared__ float ssum[16][4];
  __shared__ float part[4][16][16];

  int tid = threadIdx.x;
  int lane = tid & 63, wv = tid >> 6;
  int lr = lane & 15, lg = lane >> 4;
  int qb = blockIdx.x, n = blockIdx.y, b = blockIdx.z;
  int p0 = qb * 16;
  const size_t qkbase = ((size_t)(b * NH_ + n)) * HW_ * DKH_;

  for (int i = tid; i < 16 * DKH_; i += 256) {
    int row = i / DKH_, d = i % DKH_;
    q_lds[row][d] = qt[qkbase + (size_t)(p0 + row) * DKH_ + d];
  }
  __syncthreads();

  // rw[i][y'] = q_i . rel_w[y'-y_i+31],  rh[i][x'] = q_i . rel_h[x'-x_i+31]
  for (int e = tid; e < 1024; e += 256) {
    int i = e >> 6, rem = e & 63, which = rem >> 5, idx = rem & 31;
    int p = p0 + i;
    int coord = which ? (p >> 5) : (p & 31);
    const float* rel = which ? relh : relw;
    const float* rrow = rel + (size_t)(idx - coord + 31) * DKH_;
    float a = 0.f;
    for (int d = 0; d < DKH_; ++d) a += (float)q_lds[i][d] * rrow[d];
    if (which) rh[i][idx] = a; else rw[i][idx] = a;
  }
  __syncthreads();

  bf16x8 qf[5];
#pragma unroll
  for (int ks = 0; ks < 5; ++ks)
    qf[ks] = *(const bf16x8*)&q_lds[lr][ks * 32 + lg * 8];

  f32x4 zz = {0.f, 0.f, 0.f, 0.f};
  f32x4 acc[16];
#pragma unroll
  for (int t = 0; t < 16; ++t) acc[t] = zz;

  int key_base = wv * 256;
#pragma unroll
  for (int t = 0; t < 16; ++t) {
    const __bf16* kp = kt + qkbase + (size_t)(key_base + t * 16 + lr) * DKH_ + lg * 8;
#pragma unroll
    for (int ks = 0; ks < 5; ++ks) {
      bf16x8 kf = *(const bf16x8*)(kp + ks * 32);
      acc[t] = __builtin_amdgcn_mfma_f32_16x16x32_bf16(qf[ks], kf, acc[t], 0, 0, 0);
    }
  }

  // add relative logits: D[m=q][n=key], m = lg*4+r, key = key_base+t*16+lr
#pragma unroll
  for (int t = 0; t < 16; ++t) {
    int key = key_base + t * 16 + lr;
    int ky = key & 31, kx = key >> 5;
#pragma unroll
    for (int r = 0; r < 4; ++r)
      acc[t][r] += rw[lg * 4 + r][ky] + rh[lg * 4 + r][kx];
  }

  // softmax max (16 lanes sharing lg hold one q-row's keys)
  float mx[4];
#pragma unroll
  for (int r = 0; r < 4; ++r) {
    float m = acc[0][r];
#pragma unroll
    for (int t = 1; t < 16; ++t) m = fmaxf(m, acc[t][r]);
#pragma unroll
    for (int msk = 1; msk < 16; msk <<= 1)
      m = fmaxf(m, __shfl_xor(m, msk, 64));
    mx[r] = m;
  }
  if (lr == 0) {
#pragma unroll
    for (int r = 0; r < 4; ++r) smax[lg * 4 + r][wv] = mx[r];
  }
  __syncthreads();
  float M[4];
#pragma unroll
  for (int r = 0; r < 4; ++r) {
    int i = lg * 4 + r;
    M[r] = fmaxf(fmaxf(smax[i][0], smax[i][1]), fmaxf(smax[i][2], smax[i][3]));
  }

  float sm[4] = {0.f, 0.f, 0.f, 0.f};
#pragma unroll
  for (int t = 0; t < 16; ++t) {
#pragma unroll
    for (int r = 0; r < 4; ++r) {
      float pv = __expf(acc[t][r] - M[r]);
      __bf16 pb = (__bf16)pv;
      sm[r] += (float)pb;               // denominator consistent with bf16 P
      p_lds[wv][lg * 4 + r][t * 16 + lr] = pb;
    }
  }
#pragma unroll
  for (int r = 0; r < 4; ++r) {
#pragma unroll
    for (int msk = 1; msk < 16; msk <<= 1)
      sm[r] += __shfl_xor(sm[r], msk, 64);
  }
  if (lr == 0) {
#pragma unroll
    for (int r = 0; r < 4; ++r) ssum[lg * 4 + r][wv] = sm[r];
  }

  // PV: partial over this wave's 256 keys. X=P rows(q), Y=V^T rows(dv).
  f32x4 pv_acc = zz;
  const __bf16* vbase = vt + ((size_t)b * 64 + n * 16 + lr) * HW_ + key_base + lg * 8;
#pragma unroll
  for (int ks = 0; ks < 8; ++ks) {
    bf16x8 pf = *(const bf16x8*)&p_lds[wv][lr][ks * 32 + lg * 8];
    bf16x8 vf = *(const bf16x8*)(vbase + ks * 32);
    pv_acc = __builtin_amdgcn_mfma_f32_16x16x32_bf16(pf, vf, pv_acc, 0, 0, 0);
  }
#pragma unroll
  for (int r = 0; r < 4; ++r) part[wv][lg * 4 + r][lr] = pv_acc[r];
  __syncthreads();

  // epilogue: combine waves, divide, scatter per raw-reshape mapping
  int i = tid >> 4, dv = tid & 15;
  float s = ssum[i][0] + ssum[i][1] + ssum[i][2] + ssum[i][3];
  float val = (part[0][i][dv] + part[1][i][dv] + part[2][i][dv] + part[3][i][dv]) / s;
  int flat = (p0 + i) * 16 + dv;
  attn_out[((size_t)b * 64 + n * 16 + (flat >> 10)) * HW_ + (flat & 1023)] = (__bf16)val;
}

// ---------------------------------------------------------------------------
// 1x1 projection over the 64 attn channels -> out channels [256,320) (+resid)
// ---------------------------------------------------------------------------
template <typename TO>
__global__ __launch_bounds__(256)
void proj1x1(const __bf16* __restrict__ attn, const float* __restrict__ w,
             const float* __restrict__ bias, TO* __restrict__ out,
             const float* __restrict__ resid) {
  __shared__ float wl[64][64];
  int tid = threadIdx.x;
  int b = blockIdx.y;
  int p = blockIdx.x * 256 + tid;
  for (int i = tid; i < 4096; i += 256) wl[i >> 6][i & 63] = w[i];
  __syncthreads();
  float in[64];
#pragma unroll
  for (int c = 0; c < 64; ++c) in[c] = (float)attn[((size_t)b * 64 + c) * HW_ + p];
  for (int c = 0; c < 64; ++c) {
    float a = bias[c];
#pragma unroll
    for (int cc = 0; cc < 64; ++cc) a += wl[c][cc] * in[cc];
    size_t o = ((size_t)b * C_ + 256 + c) * HW_ + p;
    if (resid) a += resid[o];
    out[o] = (TO)a;
  }
}

// ---------------------------------------------------------------------------
extern "C" void kernel_launch(void* const* d_in, const int* in_sizes, int n_in,
                              void* d_out, int out_size, void* d_ws, size_t ws_size,
                              hipStream_t stream) {
  (void)in_sizes; (void)n_in; (void)out_size;
  const float* x = (const float*)d_in[0];
  const float* bn_g[2]   = {(const float*)d_in[1],  (const float*)d_in[5]};
  const float* bn_b[2]   = {(const float*)d_in[2],  (const float*)d_in[6]};
  const float* bn_m[2]   = {(const float*)d_in[3],  (const float*)d_in[7]};
  const float* bn_v[2]   = {(const float*)d_in[4],  (const float*)d_in[8]};
  const float* conv_w[2] = {(const float*)d_in[9],  (const float*)d_in[17]};
  const float* conv_b[2] = {(const float*)d_in[10], (const float*)d_in[18]};
  const float* qkv_w[2]  = {(const float*)d_in[11], (const float*)d_in[19]};
  const float* qkv_b[2]  = {(const float*)d_in[12], (const float*)d_in[20]};
  const float* attn_w[2] = {(const float*)d_in[13], (const float*)d_in[21]};
  const float* attn_b[2] = {(const float*)d_in[14], (const float*)d_in[22]};
  const float* rel_w[2]  = {(const float*)d_in[15], (const float*)d_in[23]};
  const float* rel_h[2]  = {(const float*)d_in[16], (const float*)d_in[24]};

  char* ws = (char*)d_ws;
  size_t off = 0;
  auto take = [&](size_t bytes) {
    char* p = ws + off;
    off += (bytes + 255) & ~(size_t)255;
    return p;
  };
  __bf16* y_nhwc = (__bf16*)take((size_t)B_ * HW_ * C_ * 2);         // 10.5 MB
  __bf16* qt     = (__bf16*)take((size_t)B_ * NH_ * HW_ * DKH_ * 2); // 21 MB
  __bf16* kt2    = (__bf16*)take((size_t)B_ * NH_ * HW_ * DKH_ * 2); // 21 MB
  __bf16* vt     = (__bf16*)take((size_t)B_ * 64 * HW_ * 2);         // 2 MB
  __bf16* attn_c = (__bf16*)take((size_t)B_ * 64 * HW_ * 2);         // 2 MB
  __bf16* l1out  = (__bf16*)take((size_t)B_ * C_ * HW_ * 2);         // 10.5 MB
  __bf16* wt_s   = (__bf16*)take((size_t)9 * QKVC * C_ * 2);         // 7.7 MB (shared)
  if (ws_size < off) return;  // diagnostic: finite-error failure => ws too small

  for (int l = 0; l < 2; ++l) {
    __bf16* outbuf_bf = l1out;
    float*  outbuf_f  = (float*)d_out;
    const float* resid = (l == 0) ? nullptr : x;

    if (l == 0)
      bn_relu_t<float><<<dim3(32, 10, 16), dim3(32, 8), 0, stream>>>(
          x, bn_g[l], bn_b[l], bn_m[l], bn_v[l], y_nhwc);
    else
      bn_relu_t<__bf16><<<dim3(32, 10, 16), dim3(32, 8), 0, stream>>>(
          l1out, bn_g[l], bn_b[l], bn_m[l], bn_v[l], y_nhwc);

    int tw1 = 9 * CO_ * C_;
    transform_w<<<(tw1 + 255) / 256, 256, 0, stream>>>(conv_w[l], wt_s, tw1, CO_);
    if (l == 0)
      conv3x3_mfma<__bf16><<<dim3(16, CO_ / 64, 16), 256, 0, stream>>>(
          y_nhwc, wt_s, conv_b[l], CO_, 0, outbuf_bf, nullptr, nullptr, nullptr, nullptr);
    else
      conv3x3_mfma<float><<<dim3(16, CO_ / 64, 16), 256, 0, stream>>>(
          y_nhwc, wt_s, conv_b[l], CO_, 0, outbuf_f, resid, nullptr, nullptr, nullptr);

    int tw2 = 9 * QKVC * C_;
    transform_w<<<(tw2 + 255) / 256, 256, 0, stream>>>(qkv_w[l], wt_s, tw2, QKVC);
    conv3x3_mfma<float><<<dim3(16, QKVC / 64, 16), 256, 0, stream>>>(
        y_nhwc, wt_s, qkv_b[l], QKVC, 1, nullptr, nullptr, qt, kt2, vt);

    attn_kernel<<<dim3(64, NH_, 16), 256, 0, stream>>>(
        qt, kt2, vt, rel_w[l], rel_h[l], attn_c);

    if (l == 0)
      proj1x1<__bf16><<<dim3(4, 16), 256, 0, stream>>>(
          attn_c, attn_w[l], attn_b[l], outbuf_bf, nullptr);
    else
      proj1x1<float><<<dim3(4, 16), 256, 0, stream>>>(
          attn_c, attn_w[l], attn_b[l], outbuf_f, resid);
  }
}

// Round 3
// 1717.559 us; speedup vs baseline: 1.7678x; 1.7678x over previous
//
#include <hip/hip_runtime.h>
#include <hip/hip_bf16.h>

// Shapes (fixed for this problem)
#define B_   16
#define C_   320
#define HW_  1024
#define CO_  256    // conv_out channels
#define NH_  4
#define DKH_ 160
#define QKVC 1344   // 2*640 + 64

using bf16x8 = __attribute__((ext_vector_type(8))) __bf16;
using f32x4  = __attribute__((ext_vector_type(4))) float;

static __device__ __forceinline__ bf16x8 bzero8() {
  bf16x8 r;
#pragma unroll
  for (int j = 0; j < 8; ++j) r[j] = (__bf16)0.0f;
  return r;
}

// ---------------------------------------------------------------------------
// Weight transform: w[co][ci][kh][kw] (fp32) -> wt[tap][co][ci] (bf16)
// ---------------------------------------------------------------------------
__global__ void transform_w(const float* __restrict__ w, __bf16* __restrict__ wt,
                            int total, int Cout) {
  int idx = blockIdx.x * 256 + threadIdx.x;
  if (idx >= total) return;
  int ci = idx % C_;
  int rest = idx / C_;
  int co = rest % Cout;
  int tap = rest / Cout;
  wt[idx] = (__bf16)w[(co * C_ + ci) * 9 + tap];
}

// ---------------------------------------------------------------------------
// BN + ReLU + NCHW->NHWC transpose.  x:[B][320][1024] -> y:[B][1024][320] bf16
// ---------------------------------------------------------------------------
template <typename TI>
__global__ __launch_bounds__(256)
void bn_relu_t(const TI* __restrict__ x, const float* __restrict__ g,
               const float* __restrict__ bb, const float* __restrict__ m,
               const float* __restrict__ v, __bf16* __restrict__ y) {
  __shared__ __bf16 tile[32][33];
  int b = blockIdx.z, c0 = blockIdx.y * 32, p0 = blockIdx.x * 32;
#pragma unroll
  for (int i = 0; i < 4; ++i) {
    int cl = threadIdx.y + i * 8;
    int c = c0 + cl;
    int p = p0 + threadIdx.x;
    float scale = g[c] * rsqrtf(v[c] + 1e-5f);
    float val = ((float)x[((size_t)b * C_ + c) * HW_ + p] - m[c]) * scale + bb[c];
    tile[cl][threadIdx.x] = (__bf16)fmaxf(val, 0.0f);
  }
  __syncthreads();
#pragma unroll
  for (int i = 0; i < 4; ++i) {
    int pl = threadIdx.y + i * 8;
    int p = p0 + pl;
    int c = c0 + threadIdx.x;
    y[((size_t)b * HW_ + p) * C_ + c] = tile[threadIdx.x][pl];
  }
}

// ---------------------------------------------------------------------------
// LDS-tiled implicit-GEMM 3x3 conv (pad=1), MFMA 16x16x32 bf16.
// Block: 256 thr / 4 waves; tile 128co x 128p (4 image rows).
// Per ci-chunk(64): stage act halo [6 rows][34 cols][64ci] once (XOR-swizzled),
// reuse across 9 taps; per tap stage W [128co][64ci] (XOR-swizzled).
// Wave w: co half = w>>1, p half = w&1; acc[4][4] 16x16 fragments.
// mode 0: out NCHW [B][C][HW] channels [0,Cout) (+resid)
// mode 1: qkv scatter into qt/kt (p-major, q scaled) and vt (NCHW)
// ---------------------------------------------------------------------------
template <typename TO>
__global__ __launch_bounds__(256)
void conv3x3_mfma(const __bf16* __restrict__ y, const __bf16* __restrict__ wt,
                  const float* __restrict__ bias, int Cout, int mode,
                  TO* __restrict__ out, const float* __restrict__ resid,
                  __bf16* __restrict__ qt, __bf16* __restrict__ kt,
                  __bf16* __restrict__ vt) {
  __shared__ __align__(16) char act_s[204 * 128];  // (6*34) slots x 128B
  __shared__ __align__(16) char w_s[128 * 128];    // 128 co x 128B

  int tid = threadIdx.x;
  int lane = tid & 63, wv = tid >> 6;
  int lr = lane & 15, lg = lane >> 4;
  int b = blockIdx.z;
  int co_blk = blockIdx.y * 128;
  int h0 = blockIdx.x * 4;           // first image row of this p-tile
  int wco = wv >> 1, wp = wv & 1;

  f32x4 zz = {0.f, 0.f, 0.f, 0.f};
  f32x4 acc[4][4];
#pragma unroll
  for (int m = 0; m < 4; ++m)
#pragma unroll
    for (int n = 0; n < 4; ++n) acc[m][n] = zz;

  // per-n fragment image coords (row/col within the staged halo, pre-tap)
  int rbase[4], cbase[4];
#pragma unroll
  for (int n = 0; n < 4; ++n) {
    int pb = wp * 64 + n * 16 + lr;      // 0..127 within block
    rbase[n] = (pb >> 5) + 1;            // +1 halo offset
    cbase[n] = (pb & 31) + 1;
  }

  const __bf16* ybase = y + (size_t)b * HW_ * C_;

  for (int cb = 0; cb < 5; ++cb) {
    int ci0 = cb * 64;
    // ---- stage activation halo (covered by the tap-0 barrier below) ----
    for (int g = tid; g < 1632; g += 256) {
      int gi = g & 7, slot = g >> 3;
      int row = slot / 34, col = slot - row * 34;
      int h = h0 + row - 1, c = col - 1;
      bf16x8 val;
      if ((unsigned)h < 32u && (unsigned)c < 32u)
        val = *(const bf16x8*)(ybase + ((size_t)(h * 32 + c)) * C_ + ci0 + gi * 8);
      else
        val = bzero8();
      *(bf16x8*)(act_s + ((slot * 128 + gi * 16) ^ ((col & 7) << 4))) = val;
    }
    for (int tap = 0; tap < 9; ++tap) {
      // ---- stage weight tile [128][64] ----
      for (int e = tid; e < 1024; e += 256) {
        int gi = e & 7, co = e >> 3;
        int gco = co_blk + co;
        bf16x8 val = (gco < Cout)
            ? *(const bf16x8*)(wt + ((size_t)tap * Cout + gco) * C_ + ci0 + gi * 8)
            : bzero8();
        *(bf16x8*)(w_s + ((co * 128 + gi * 16) ^ ((co & 7) << 4))) = val;
      }
      __syncthreads();   // staging (act for tap==0, W always) complete
      int dh = tap / 3 - 1, dw = tap % 3 - 1;
#pragma unroll
      for (int ks = 0; ks < 2; ++ks) {
        bf16x8 af[4], bfv[4];
#pragma unroll
        for (int m = 0; m < 4; ++m) {
          int co_l = wco * 64 + m * 16 + lr;
          af[m] = *(const bf16x8*)(w_s + ((co_l * 128 + ks * 64 + lg * 16) ^ ((co_l & 7) << 4)));
        }
#pragma unroll
        for (int n = 0; n < 4; ++n) {
          int row = rbase[n] + dh, col = cbase[n] + dw;
          bfv[n] = *(const bf16x8*)(act_s + (((row * 34 + col) * 128 + ks * 64 + lg * 16) ^ ((col & 7) << 4)));
        }
#pragma unroll
        for (int m = 0; m < 4; ++m)
#pragma unroll
          for (int n = 0; n < 4; ++n)
            acc[m][n] = __builtin_amdgcn_mfma_f32_16x16x32_bf16(af[m], bfv[n], acc[m][n], 0, 0, 0);
      }
      __syncthreads();   // compute done -> next stage may overwrite
    }
  }

  const float scaleq = 0.07905694150420949f; // 160^-0.5
  int p_blk = blockIdx.x * 128;
#pragma unroll
  for (int m = 0; m < 4; ++m) {
#pragma unroll
    for (int n = 0; n < 4; ++n) {
#pragma unroll
      for (int r = 0; r < 4; ++r) {
        int co = co_blk + wco * 64 + m * 16 + lg * 4 + r;
        if (co >= Cout) continue;
        int p = p_blk + wp * 64 + n * 16 + lr;
        float val = acc[m][n][r] + bias[co];
        if (mode == 0) {
          size_t o = ((size_t)b * C_ + co) * HW_ + p;
          if (resid) val += resid[o];
          out[o] = (TO)val;
        } else {
          if (co < 640) {
            int nn = co / DKH_, d = co % DKH_;
            qt[(((size_t)b * NH_ + nn) * HW_ + p) * DKH_ + d] = (__bf16)(val * scaleq);
          } else if (co < 1280) {
            int c2 = co - 640;
            int nn = c2 / DKH_, d = c2 % DKH_;
            kt[(((size_t)b * NH_ + nn) * HW_ + p) * DKH_ + d] = (__bf16)val;
          } else {
            int c3 = co - 1280;
            vt[((size_t)b * 64 + c3) * HW_ + p] = (__bf16)val;
          }
        }
      }
    }
  }
}

// ---------------------------------------------------------------------------
// Fused attention per (b, head, 16-query block).
// logits = q.k + q.rel_w[y'-y+31] + q.rel_h[x'-x+31]; softmax; P@V; scatter
// per the reference's raw reshape (b,NH,HW,dvh)->(b,64,H,W).
// 256 threads / 4 waves; wave w owns keys [w*256, w*256+256).
// ---------------------------------------------------------------------------
__global__ __launch_bounds__(256)
void attn_kernel(const __bf16* __restrict__ qt, const __bf16* __restrict__ kt,
                 const __bf16* __restrict__ vt, const float* __restrict__ relw,
                 const float* __restrict__ relh, __bf16* __restrict__ attn_out) {
  __shared__ __align__(16) __bf16 q_lds[16][168];   // pad 8 bf16
  __shared__ float rw[16][32];
  __shared__ float rh[16][32];
  __shared__ __align__(16) __bf16 p_lds[4][16][264]; // per-wave P, pad 8
  __shared__ float smax[16][4];
  __shared__ float ssum[16][4];
  __shared__ float part[4][16][16];

  int tid = threadIdx.x;
  int lane = tid & 63, wv = tid >> 6;
  int lr = lane & 15, lg = lane >> 4;
  int qb = blockIdx.x, n = blockIdx.y, b = blockIdx.z;
  int p0 = qb * 16;
  const size_t qkbase = ((size_t)(b * NH_ + n)) * HW_ * DKH_;

  for (int i = tid; i < 16 * DKH_; i += 256) {
    int row = i / DKH_, d = i % DKH_;
    q_lds[row][d] = qt[qkbase + (size_t)(p0 + row) * DKH_ + d];
  }
  __syncthreads();

  // rw[i][y'] = q_i . rel_w[y'-y_i+31],  rh[i][x'] = q_i . rel_h[x'-x_i+31]
  for (int e = tid; e < 1024; e += 256) {
    int i = e >> 6, rem = e & 63, which = rem >> 5, idx = rem & 31;
    int p = p0 + i;
    int coord = which ? (p >> 5) : (p & 31);
    const float* rel = which ? relh : relw;
    const float* rrow = rel + (size_t)(idx - coord + 31) * DKH_;
    float a = 0.f;
    for (int d = 0; d < DKH_; ++d) a += (float)q_lds[i][d] * rrow[d];
    if (which) rh[i][idx] = a; else rw[i][idx] = a;
  }
  __syncthreads();

  bf16x8 qf[5];
#pragma unroll
  for (int ks = 0; ks < 5; ++ks)
    qf[ks] = *(const bf16x8*)&q_lds[lr][ks * 32 + lg * 8];

  f32x4 zz = {0.f, 0.f, 0.f, 0.f};
  f32x4 acc[16];
#pragma unroll
  for (int t = 0; t < 16; ++t) acc[t] = zz;

  int key_base = wv * 256;
#pragma unroll
  for (int t = 0; t < 16; ++t) {
    const __bf16* kp = kt + qkbase + (size_t)(key_base + t * 16 + lr) * DKH_ + lg * 8;
#pragma unroll
    for (int ks = 0; ks < 5; ++ks) {
      bf16x8 kf = *(const bf16x8*)(kp + ks * 32);
      acc[t] = __builtin_amdgcn_mfma_f32_16x16x32_bf16(qf[ks], kf, acc[t], 0, 0, 0);
    }
  }

  // add relative logits: D[m=q][n=key], m = lg*4+r, key = key_base+t*16+lr
#pragma unroll
  for (int t = 0; t < 16; ++t) {
    int key = key_base + t * 16 + lr;
    int ky = key & 31, kx = key >> 5;
#pragma unroll
    for (int r = 0; r < 4; ++r)
      acc[t][r] += rw[lg * 4 + r][ky] + rh[lg * 4 + r][kx];
  }

  // softmax max (16 lanes sharing lg hold one q-row's keys)
  float mx[4];
#pragma unroll
  for (int r = 0; r < 4; ++r) {
    float m = acc[0][r];
#pragma unroll
    for (int t = 1; t < 16; ++t) m = fmaxf(m, acc[t][r]);
#pragma unroll
    for (int msk = 1; msk < 16; msk <<= 1)
      m = fmaxf(m, __shfl_xor(m, msk, 64));
    mx[r] = m;
  }
  if (lr == 0) {
#pragma unroll
    for (int r = 0; r < 4; ++r) smax[lg * 4 + r][wv] = mx[r];
  }
  __syncthreads();
  float M[4];
#pragma unroll
  for (int r = 0; r < 4; ++r) {
    int i = lg * 4 + r;
    M[r] = fmaxf(fmaxf(smax[i][0], smax[i][1]), fmaxf(smax[i][2], smax[i][3]));
  }

  float sm[4] = {0.f, 0.f, 0.f, 0.f};
#pragma unroll
  for (int t = 0; t < 16; ++t) {
#pragma unroll
    for (int r = 0; r < 4; ++r) {
      float pv = __expf(acc[t][r] - M[r]);
      __bf16 pb = (__bf16)pv;
      sm[r] += (float)pb;               // denominator consistent with bf16 P
      p_lds[wv][lg * 4 + r][t * 16 + lr] = pb;
    }
  }
#pragma unroll
  for (int r = 0; r < 4; ++r) {
#pragma unroll
    for (int msk = 1; msk < 16; msk <<= 1)
      sm[r] += __shfl_xor(sm[r], msk, 64);
  }
  if (lr == 0) {
#pragma unroll
    for (int r = 0; r < 4; ++r) ssum[lg * 4 + r][wv] = sm[r];
  }

  // PV: partial over this wave's 256 keys. X=P rows(q), Y=V^T rows(dv).
  f32x4 pv_acc = zz;
  const __bf16* vbase = vt + ((size_t)b * 64 + n * 16 + lr) * HW_ + key_base + lg * 8;
#pragma unroll
  for (int ks = 0; ks < 8; ++ks) {
    bf16x8 pf = *(const bf16x8*)&p_lds[wv][lr][ks * 32 + lg * 8];
    bf16x8 vf = *(const bf16x8*)(vbase + ks * 32);
    pv_acc = __builtin_amdgcn_mfma_f32_16x16x32_bf16(pf, vf, pv_acc, 0, 0, 0);
  }
#pragma unroll
  for (int r = 0; r < 4; ++r) part[wv][lg * 4 + r][lr] = pv_acc[r];
  __syncthreads();

  // epilogue: combine waves, divide, scatter per raw-reshape mapping
  int i = tid >> 4, dv = tid & 15;
  float s = ssum[i][0] + ssum[i][1] + ssum[i][2] + ssum[i][3];
  float val = (part[0][i][dv] + part[1][i][dv] + part[2][i][dv] + part[3][i][dv]) / s;
  int flat = (p0 + i) * 16 + dv;
  attn_out[((size_t)b * 64 + n * 16 + (flat >> 10)) * HW_ + (flat & 1023)] = (__bf16)val;
}

// ---------------------------------------------------------------------------
// 1x1 projection over the 64 attn channels -> out channels [256,320) (+resid)
// ---------------------------------------------------------------------------
template <typename TO>
__global__ __launch_bounds__(256)
void proj1x1(const __bf16* __restrict__ attn, const float* __restrict__ w,
             const float* __restrict__ bias, TO* __restrict__ out,
             const float* __restrict__ resid) {
  __shared__ float wl[64][64];
  int tid = threadIdx.x;
  int b = blockIdx.y;
  int p = blockIdx.x * 256 + tid;
  for (int i = tid; i < 4096; i += 256) wl[i >> 6][i & 63] = w[i];
  __syncthreads();
  float in[64];
#pragma unroll
  for (int c = 0; c < 64; ++c) in[c] = (float)attn[((size_t)b * 64 + c) * HW_ + p];
  for (int c = 0; c < 64; ++c) {
    float a = bias[c];
#pragma unroll
    for (int cc = 0; cc < 64; ++cc) a += wl[c][cc] * in[cc];
    size_t o = ((size_t)b * C_ + 256 + c) * HW_ + p;
    if (resid) a += resid[o];
    out[o] = (TO)a;
  }
}

// ---------------------------------------------------------------------------
extern "C" void kernel_launch(void* const* d_in, const int* in_sizes, int n_in,
                              void* d_out, int out_size, void* d_ws, size_t ws_size,
                              hipStream_t stream) {
  (void)in_sizes; (void)n_in; (void)out_size;
  const float* x = (const float*)d_in[0];
  const float* bn_g[2]   = {(const float*)d_in[1],  (const float*)d_in[5]};
  const float* bn_b[2]   = {(const float*)d_in[2],  (const float*)d_in[6]};
  const float* bn_m[2]   = {(const float*)d_in[3],  (const float*)d_in[7]};
  const float* bn_v[2]   = {(const float*)d_in[4],  (const float*)d_in[8]};
  const float* conv_w[2] = {(const float*)d_in[9],  (const float*)d_in[17]};
  const float* conv_b[2] = {(const float*)d_in[10], (const float*)d_in[18]};
  const float* qkv_w[2]  = {(const float*)d_in[11], (const float*)d_in[19]};
  const float* qkv_b[2]  = {(const float*)d_in[12], (const float*)d_in[20]};
  const float* attn_w[2] = {(const float*)d_in[13], (const float*)d_in[21]};
  const float* attn_b[2] = {(const float*)d_in[14], (const float*)d_in[22]};
  const float* rel_w[2]  = {(const float*)d_in[15], (const float*)d_in[23]};
  const float* rel_h[2]  = {(const float*)d_in[16], (const float*)d_in[24]};

  char* ws = (char*)d_ws;
  size_t off = 0;
  auto take = [&](size_t bytes) {
    char* p = ws + off;
    off += (bytes + 255) & ~(size_t)255;
    return p;
  };
  __bf16* y_nhwc = (__bf16*)take((size_t)B_ * HW_ * C_ * 2);         // 10.5 MB
  __bf16* qt     = (__bf16*)take((size_t)B_ * NH_ * HW_ * DKH_ * 2); // 21 MB
  __bf16* kt2    = (__bf16*)take((size_t)B_ * NH_ * HW_ * DKH_ * 2); // 21 MB
  __bf16* vt     = (__bf16*)take((size_t)B_ * 64 * HW_ * 2);         // 2 MB
  __bf16* attn_c = (__bf16*)take((size_t)B_ * 64 * HW_ * 2);         // 2 MB
  __bf16* l1out  = (__bf16*)take((size_t)B_ * C_ * HW_ * 2);         // 10.5 MB
  __bf16* wt_s   = (__bf16*)take((size_t)9 * QKVC * C_ * 2);         // 7.7 MB (shared)
  if (ws_size < off) return;  // diagnostic: finite-error failure => ws too small

  for (int l = 0; l < 2; ++l) {
    __bf16* outbuf_bf = l1out;
    float*  outbuf_f  = (float*)d_out;
    const float* resid = (l == 0) ? nullptr : x;

    if (l == 0)
      bn_relu_t<float><<<dim3(32, 10, 16), dim3(32, 8), 0, stream>>>(
          x, bn_g[l], bn_b[l], bn_m[l], bn_v[l], y_nhwc);
    else
      bn_relu_t<__bf16><<<dim3(32, 10, 16), dim3(32, 8), 0, stream>>>(
          l1out, bn_g[l], bn_b[l], bn_m[l], bn_v[l], y_nhwc);

    int tw1 = 9 * CO_ * C_;
    transform_w<<<(tw1 + 255) / 256, 256, 0, stream>>>(conv_w[l], wt_s, tw1, CO_);
    if (l == 0)
      conv3x3_mfma<__bf16><<<dim3(8, 2, 16), 256, 0, stream>>>(
          y_nhwc, wt_s, conv_b[l], CO_, 0, outbuf_bf, nullptr, nullptr, nullptr, nullptr);
    else
      conv3x3_mfma<float><<<dim3(8, 2, 16), 256, 0, stream>>>(
          y_nhwc, wt_s, conv_b[l], CO_, 0, outbuf_f, resid, nullptr, nullptr, nullptr);

    int tw2 = 9 * QKVC * C_;
    transform_w<<<(tw2 + 255) / 256, 256, 0, stream>>>(qkv_w[l], wt_s, tw2, QKVC);
    conv3x3_mfma<float><<<dim3(8, 11, 16), 256, 0, stream>>>(
        y_nhwc, wt_s, qkv_b[l], QKVC, 1, nullptr, nullptr, qt, kt2, vt);

    attn_kernel<<<dim3(64, NH_, 16), 256, 0, stream>>>(
        qt, kt2, vt, rel_w[l], rel_h[l], attn_c);

    if (l == 0)
      proj1x1<__bf16><<<dim3(4, 16), 256, 0, stream>>>(
          attn_c, attn_w[l], attn_b[l], outbuf_bf, nullptr);
    else
      proj1x1<float><<<dim3(4, 16), 256, 0, stream>>>(
          attn_c, attn_w[l], attn_b[l], outbuf_f, resid);
  }
}

// Round 4
// 1178.324 us; speedup vs baseline: 2.5769x; 1.4576x over previous
//
#include <hip/hip_runtime.h>
#include <hip/hip_bf16.h>

// Shapes (fixed for this problem)
#define B_   16
#define C_   320
#define HW_  1024
#define CO_  256    // conv_out channels
#define NH_  4
#define DKH_ 160
#define QKVC 1344   // 2*640 + 64

using bf16x8 = __attribute__((ext_vector_type(8))) __bf16;
using f32x4  = __attribute__((ext_vector_type(4))) float;

static __device__ __forceinline__ bf16x8 bzero8() {
  bf16x8 r;
#pragma unroll
  for (int j = 0; j < 8; ++j) r[j] = (__bf16)0.0f;
  return r;
}

// ---------------------------------------------------------------------------
// Weight transform: w[co][ci][kh][kw] (fp32) -> wt[tap][co][ci] (bf16)
// ---------------------------------------------------------------------------
__global__ void transform_w(const float* __restrict__ w, __bf16* __restrict__ wt,
                            int total, int Cout) {
  int idx = blockIdx.x * 256 + threadIdx.x;
  if (idx >= total) return;
  int ci = idx % C_;
  int rest = idx / C_;
  int co = rest % Cout;
  int tap = rest / Cout;
  wt[idx] = (__bf16)w[(co * C_ + ci) * 9 + tap];
}

// ---------------------------------------------------------------------------
// BN + ReLU + NCHW->NHWC transpose.  x:[B][320][1024] -> y:[B][1024][320] bf16
// ---------------------------------------------------------------------------
template <typename TI>
__global__ __launch_bounds__(256)
void bn_relu_t(const TI* __restrict__ x, const float* __restrict__ g,
               const float* __restrict__ bb, const float* __restrict__ m,
               const float* __restrict__ v, __bf16* __restrict__ y) {
  __shared__ __bf16 tile[32][33];
  int b = blockIdx.z, c0 = blockIdx.y * 32, p0 = blockIdx.x * 32;
#pragma unroll
  for (int i = 0; i < 4; ++i) {
    int cl = threadIdx.y + i * 8;
    int c = c0 + cl;
    int p = p0 + threadIdx.x;
    float scale = g[c] * rsqrtf(v[c] + 1e-5f);
    float val = ((float)x[((size_t)b * C_ + c) * HW_ + p] - m[c]) * scale + bb[c];
    tile[cl][threadIdx.x] = (__bf16)fmaxf(val, 0.0f);
  }
  __syncthreads();
#pragma unroll
  for (int i = 0; i < 4; ++i) {
    int pl = threadIdx.y + i * 8;
    int p = p0 + pl;
    int c = c0 + threadIdx.x;
    y[((size_t)b * HW_ + p) * C_ + c] = tile[threadIdx.x][pl];
  }
}

// ---------------------------------------------------------------------------
// LDS-tiled implicit-GEMM 3x3 conv (pad=1), MFMA 16x16x32 bf16.
// Block: 256 thr / 4 waves; tile 128co x 128p (4 image rows).
// Per ci-chunk(64): stage act halo [6 rows][34 cols][64ci] once (XOR-swizzled),
// reuse across 9 taps; per tap stage W [128co][64ci] (XOR-swizzled).
// Wave w: co half = w>>1, p half = w&1; acc[4][4] 16x16 fragments.
// mode 0: out NCHW [B][C][HW] channels [0,Cout) (+resid)
// mode 1: qkv scatter into qt/kt (p-major, q scaled) and vt (NCHW)
// ---------------------------------------------------------------------------
template <typename TO>
__global__ __launch_bounds__(256)
void conv3x3_mfma(const __bf16* __restrict__ y, const __bf16* __restrict__ wt,
                  const float* __restrict__ bias, int Cout, int mode,
                  TO* __restrict__ out, const float* __restrict__ resid,
                  __bf16* __restrict__ qt, __bf16* __restrict__ kt,
                  __bf16* __restrict__ vt) {
  __shared__ __align__(16) char act_s[204 * 128];  // (6*34) slots x 128B
  __shared__ __align__(16) char w_s[128 * 128];    // 128 co x 128B

  int tid = threadIdx.x;
  int lane = tid & 63, wv = tid >> 6;
  int lr = lane & 15, lg = lane >> 4;
  int b = blockIdx.z;
  int co_blk = blockIdx.y * 128;
  int h0 = blockIdx.x * 4;           // first image row of this p-tile
  int wco = wv >> 1, wp = wv & 1;

  f32x4 zz = {0.f, 0.f, 0.f, 0.f};
  f32x4 acc[4][4];
#pragma unroll
  for (int m = 0; m < 4; ++m)
#pragma unroll
    for (int n = 0; n < 4; ++n) acc[m][n] = zz;

  // per-n fragment image coords (row/col within the staged halo, pre-tap)
  int rbase[4], cbase[4];
#pragma unroll
  for (int n = 0; n < 4; ++n) {
    int pb = wp * 64 + n * 16 + lr;      // 0..127 within block
    rbase[n] = (pb >> 5) + 1;            // +1 halo offset
    cbase[n] = (pb & 31) + 1;
  }

  const __bf16* ybase = y + (size_t)b * HW_ * C_;

  for (int cb = 0; cb < 5; ++cb) {
    int ci0 = cb * 64;
    // ---- stage activation halo (covered by the tap-0 barrier below) ----
    for (int g = tid; g < 1632; g += 256) {
      int gi = g & 7, slot = g >> 3;
      int row = slot / 34, col = slot - row * 34;
      int h = h0 + row - 1, c = col - 1;
      bf16x8 val;
      if ((unsigned)h < 32u && (unsigned)c < 32u)
        val = *(const bf16x8*)(ybase + ((size_t)(h * 32 + c)) * C_ + ci0 + gi * 8);
      else
        val = bzero8();
      *(bf16x8*)(act_s + ((slot * 128 + gi * 16) ^ ((col & 7) << 4))) = val;
    }
    for (int tap = 0; tap < 9; ++tap) {
      // ---- stage weight tile [128][64] ----
      for (int e = tid; e < 1024; e += 256) {
        int gi = e & 7, co = e >> 3;
        int gco = co_blk + co;
        bf16x8 val = (gco < Cout)
            ? *(const bf16x8*)(wt + ((size_t)tap * Cout + gco) * C_ + ci0 + gi * 8)
            : bzero8();
        *(bf16x8*)(w_s + ((co * 128 + gi * 16) ^ ((co & 7) << 4))) = val;
      }
      __syncthreads();   // staging (act for tap==0, W always) complete
      int dh = tap / 3 - 1, dw = tap % 3 - 1;
#pragma unroll
      for (int ks = 0; ks < 2; ++ks) {
        bf16x8 af[4], bfv[4];
#pragma unroll
        for (int m = 0; m < 4; ++m) {
          int co_l = wco * 64 + m * 16 + lr;
          af[m] = *(const bf16x8*)(w_s + ((co_l * 128 + ks * 64 + lg * 16) ^ ((co_l & 7) << 4)));
        }
#pragma unroll
        for (int n = 0; n < 4; ++n) {
          int row = rbase[n] + dh, col = cbase[n] + dw;
          bfv[n] = *(const bf16x8*)(act_s + (((row * 34 + col) * 128 + ks * 64 + lg * 16) ^ ((col & 7) << 4)));
        }
#pragma unroll
        for (int m = 0; m < 4; ++m)
#pragma unroll
          for (int n = 0; n < 4; ++n)
            acc[m][n] = __builtin_amdgcn_mfma_f32_16x16x32_bf16(af[m], bfv[n], acc[m][n], 0, 0, 0);
      }
      __syncthreads();   // compute done -> next stage may overwrite
    }
  }

  const float scaleq = 0.07905694150420949f; // 160^-0.5
  int p_blk = blockIdx.x * 128;
#pragma unroll
  for (int m = 0; m < 4; ++m) {
#pragma unroll
    for (int n = 0; n < 4; ++n) {
#pragma unroll
      for (int r = 0; r < 4; ++r) {
        int co = co_blk + wco * 64 + m * 16 + lg * 4 + r;
        if (co >= Cout) continue;
        int p = p_blk + wp * 64 + n * 16 + lr;
        float val = acc[m][n][r] + bias[co];
        if (mode == 0) {
          size_t o = ((size_t)b * C_ + co) * HW_ + p;
          if (resid) val += resid[o];
          out[o] = (TO)val;
        } else {
          if (co < 640) {
            int nn = co / DKH_, d = co % DKH_;
            qt[(((size_t)b * NH_ + nn) * HW_ + p) * DKH_ + d] = (__bf16)(val * scaleq);
          } else if (co < 1280) {
            int c2 = co - 640;
            int nn = c2 / DKH_, d = c2 % DKH_;
            kt[(((size_t)b * NH_ + nn) * HW_ + p) * DKH_ + d] = (__bf16)val;
          } else {
            int c3 = co - 1280;
            vt[((size_t)b * 64 + c3) * HW_ + p] = (__bf16)val;
          }
        }
      }
    }
  }
}

// ---------------------------------------------------------------------------
// Fused attention per (b, head, 16-query block).
// logits = q.k + q.rel_w[y'-y+31] + q.rel_h[x'-x+31]; softmax; P@V; scatter
// per the reference's raw reshape (b,NH,HW,dvh)->(b,64,H,W).
// 256 threads / 4 waves; wave w owns keys [w*256, w*256+256).
// Rel tables computed by MFMA: Rw[16q][63pos] = Q . rel_w^T (wave wv owns
// the 16-col tile wv), then logit add is a 2x f32 LDS gather.
// ---------------------------------------------------------------------------
__global__ __launch_bounds__(256)
void attn_kernel(const __bf16* __restrict__ qt, const __bf16* __restrict__ kt,
                 const __bf16* __restrict__ vt, const float* __restrict__ relw,
                 const float* __restrict__ relh, __bf16* __restrict__ attn_out) {
  __shared__ float Rw_lds[16][66];
  __shared__ float Rh_lds[16][66];
  __shared__ __align__(16) __bf16 p_lds[4][16][264]; // per-wave P, pad 8
  __shared__ float smax[16][4];
  __shared__ float ssum[16][4];
  __shared__ float part[4][16][16];

  int tid = threadIdx.x;
  int lane = tid & 63, wv = tid >> 6;
  int lr = lane & 15, lg = lane >> 4;
  int qb = blockIdx.x, n = blockIdx.y, b = blockIdx.z;
  int p0 = qb * 16;
  const size_t qkbase = ((size_t)(b * NH_ + n)) * HW_ * DKH_;

  // Q fragments straight from global: lane holds q row lr, elems ks*32+lg*8..
  bf16x8 qf[5];
#pragma unroll
  for (int ks = 0; ks < 5; ++ks)
    qf[ks] = *(const bf16x8*)(qt + qkbase + (size_t)(p0 + lr) * DKH_ + ks * 32 + lg * 8);

  f32x4 zz = {0.f, 0.f, 0.f, 0.f};

  // Rel tables via MFMA: wave wv computes cols [wv*16, wv*16+16) of both.
  {
    int relpos = wv * 16 + lr;
    f32x4 accw = zz, acch = zz;
#pragma unroll
    for (int ks = 0; ks < 5; ++ks) {
      bf16x8 bw, bh;
      if (relpos < 63) {
        const float* pw = relw + (size_t)relpos * DKH_ + ks * 32 + lg * 8;
        const float* ph = relh + (size_t)relpos * DKH_ + ks * 32 + lg * 8;
#pragma unroll
        for (int j = 0; j < 8; ++j) { bw[j] = (__bf16)pw[j]; bh[j] = (__bf16)ph[j]; }
      } else { bw = bzero8(); bh = bzero8(); }
      accw = __builtin_amdgcn_mfma_f32_16x16x32_bf16(qf[ks], bw, accw, 0, 0, 0);
      acch = __builtin_amdgcn_mfma_f32_16x16x32_bf16(qf[ks], bh, acch, 0, 0, 0);
    }
#pragma unroll
    for (int r = 0; r < 4; ++r) {
      Rw_lds[lg * 4 + r][wv * 16 + lr] = accw[r];
      Rh_lds[lg * 4 + r][wv * 16 + lr] = acch[r];
    }
  }
  __syncthreads();   // Rw/Rh complete before gather below

  f32x4 acc[16];
#pragma unroll
  for (int t = 0; t < 16; ++t) acc[t] = zz;

  int key_base = wv * 256;
#pragma unroll
  for (int t = 0; t < 16; ++t) {
    const __bf16* kp = kt + qkbase + (size_t)(key_base + t * 16 + lr) * DKH_ + lg * 8;
#pragma unroll
    for (int ks = 0; ks < 5; ++ks) {
      bf16x8 kf = *(const bf16x8*)(kp + ks * 32);
      acc[t] = __builtin_amdgcn_mfma_f32_16x16x32_bf16(qf[ks], kf, acc[t], 0, 0, 0);
    }
  }

  // add relative logits: D[m=q][n=key], m = lg*4+r, key = key_base+t*16+lr
#pragma unroll
  for (int t = 0; t < 16; ++t) {
    int key = key_base + t * 16 + lr;
    int ky = key & 31, kx = key >> 5;
#pragma unroll
    for (int r = 0; r < 4; ++r) {
      int i = lg * 4 + r;
      int yi = (p0 + i) & 31, xi = (p0 + i) >> 5;
      acc[t][r] += Rw_lds[i][ky - yi + 31] + Rh_lds[i][kx - xi + 31];
    }
  }

  // softmax max (16 lanes sharing lg hold one q-row's keys)
  float mx[4];
#pragma unroll
  for (int r = 0; r < 4; ++r) {
    float m = acc[0][r];
#pragma unroll
    for (int t = 1; t < 16; ++t) m = fmaxf(m, acc[t][r]);
#pragma unroll
    for (int msk = 1; msk < 16; msk <<= 1)
      m = fmaxf(m, __shfl_xor(m, msk, 64));
    mx[r] = m;
  }
  if (lr == 0) {
#pragma unroll
    for (int r = 0; r < 4; ++r) smax[lg * 4 + r][wv] = mx[r];
  }
  __syncthreads();
  float M[4];
#pragma unroll
  for (int r = 0; r < 4; ++r) {
    int i = lg * 4 + r;
    M[r] = fmaxf(fmaxf(smax[i][0], smax[i][1]), fmaxf(smax[i][2], smax[i][3]));
  }

  float sm[4] = {0.f, 0.f, 0.f, 0.f};
#pragma unroll
  for (int t = 0; t < 16; ++t) {
#pragma unroll
    for (int r = 0; r < 4; ++r) {
      float pv = __expf(acc[t][r] - M[r]);
      __bf16 pb = (__bf16)pv;
      sm[r] += (float)pb;               // denominator consistent with bf16 P
      p_lds[wv][lg * 4 + r][t * 16 + lr] = pb;
    }
  }
#pragma unroll
  for (int r = 0; r < 4; ++r) {
#pragma unroll
    for (int msk = 1; msk < 16; msk <<= 1)
      sm[r] += __shfl_xor(sm[r], msk, 64);
  }
  if (lr == 0) {
#pragma unroll
    for (int r = 0; r < 4; ++r) ssum[lg * 4 + r][wv] = sm[r];
  }

  // PV: partial over this wave's 256 keys. X=P rows(q), Y=V^T rows(dv).
  f32x4 pv_acc = zz;
  const __bf16* vbase = vt + ((size_t)b * 64 + n * 16 + lr) * HW_ + key_base + lg * 8;
#pragma unroll
  for (int ks = 0; ks < 8; ++ks) {
    bf16x8 pf = *(const bf16x8*)&p_lds[wv][lr][ks * 32 + lg * 8];
    bf16x8 vf = *(const bf16x8*)(vbase + ks * 32);
    pv_acc = __builtin_amdgcn_mfma_f32_16x16x32_bf16(pf, vf, pv_acc, 0, 0, 0);
  }
#pragma unroll
  for (int r = 0; r < 4; ++r) part[wv][lg * 4 + r][lr] = pv_acc[r];
  __syncthreads();

  // epilogue: combine waves, divide, scatter per raw-reshape mapping
  int i = tid >> 4, dv = tid & 15;
  float s = ssum[i][0] + ssum[i][1] + ssum[i][2] + ssum[i][3];
  float val = (part[0][i][dv] + part[1][i][dv] + part[2][i][dv] + part[3][i][dv]) / s;
  int flat = (p0 + i) * 16 + dv;
  attn_out[((size_t)b * 64 + n * 16 + (flat >> 10)) * HW_ + (flat & 1023)] = (__bf16)val;
}

// ---------------------------------------------------------------------------
// 1x1 projection over the 64 attn channels -> out channels [256,320) (+resid)
// ---------------------------------------------------------------------------
template <typename TO>
__global__ __launch_bounds__(256)
void proj1x1(const __bf16* __restrict__ attn, const float* __restrict__ w,
             const float* __restrict__ bias, TO* __restrict__ out,
             const float* __restrict__ resid) {
  __shared__ float wl[64][64];
  int tid = threadIdx.x;
  int b = blockIdx.y;
  int p = blockIdx.x * 256 + tid;
  for (int i = tid; i < 4096; i += 256) wl[i >> 6][i & 63] = w[i];
  __syncthreads();
  float in[64];
#pragma unroll
  for (int c = 0; c < 64; ++c) in[c] = (float)attn[((size_t)b * 64 + c) * HW_ + p];
  for (int c = 0; c < 64; ++c) {
    float a = bias[c];
#pragma unroll
    for (int cc = 0; cc < 64; ++cc) a += wl[c][cc] * in[cc];
    size_t o = ((size_t)b * C_ + 256 + c) * HW_ + p;
    if (resid) a += resid[o];
    out[o] = (TO)a;
  }
}

// ---------------------------------------------------------------------------
extern "C" void kernel_launch(void* const* d_in, const int* in_sizes, int n_in,
                              void* d_out, int out_size, void* d_ws, size_t ws_size,
                              hipStream_t stream) {
  (void)in_sizes; (void)n_in; (void)out_size;
  const float* x = (const float*)d_in[0];
  const float* bn_g[2]   = {(const float*)d_in[1],  (const float*)d_in[5]};
  const float* bn_b[2]   = {(const float*)d_in[2],  (const float*)d_in[6]};
  const float* bn_m[2]   = {(const float*)d_in[3],  (const float*)d_in[7]};
  const float* bn_v[2]   = {(const float*)d_in[4],  (const float*)d_in[8]};
  const float* conv_w[2] = {(const float*)d_in[9],  (const float*)d_in[17]};
  const float* conv_b[2] = {(const float*)d_in[10], (const float*)d_in[18]};
  const float* qkv_w[2]  = {(const float*)d_in[11], (const float*)d_in[19]};
  const float* qkv_b[2]  = {(const float*)d_in[12], (const float*)d_in[20]};
  const float* attn_w[2] = {(const float*)d_in[13], (const float*)d_in[21]};
  const float* attn_b[2] = {(const float*)d_in[14], (const float*)d_in[22]};
  const float* rel_w[2]  = {(const float*)d_in[15], (const float*)d_in[23]};
  const float* rel_h[2]  = {(const float*)d_in[16], (const float*)d_in[24]};

  char* ws = (char*)d_ws;
  size_t off = 0;
  auto take = [&](size_t bytes) {
    char* p = ws + off;
    off += (bytes + 255) & ~(size_t)255;
    return p;
  };
  __bf16* y_nhwc = (__bf16*)take((size_t)B_ * HW_ * C_ * 2);         // 10.5 MB
  __bf16* qt     = (__bf16*)take((size_t)B_ * NH_ * HW_ * DKH_ * 2); // 21 MB
  __bf16* kt2    = (__bf16*)take((size_t)B_ * NH_ * HW_ * DKH_ * 2); // 21 MB
  __bf16* vt     = (__bf16*)take((size_t)B_ * 64 * HW_ * 2);         // 2 MB
  __bf16* attn_c = (__bf16*)take((size_t)B_ * 64 * HW_ * 2);         // 2 MB
  __bf16* l1out  = (__bf16*)take((size_t)B_ * C_ * HW_ * 2);         // 10.5 MB
  __bf16* wt_s   = (__bf16*)take((size_t)9 * QKVC * C_ * 2);         // 7.7 MB (shared)
  if (ws_size < off) return;  // diagnostic: finite-error failure => ws too small

  for (int l = 0; l < 2; ++l) {
    __bf16* outbuf_bf = l1out;
    float*  outbuf_f  = (float*)d_out;
    const float* resid = (l == 0) ? nullptr : x;

    if (l == 0)
      bn_relu_t<float><<<dim3(32, 10, 16), dim3(32, 8), 0, stream>>>(
          x, bn_g[l], bn_b[l], bn_m[l], bn_v[l], y_nhwc);
    else
      bn_relu_t<__bf16><<<dim3(32, 10, 16), dim3(32, 8), 0, stream>>>(
          l1out, bn_g[l], bn_b[l], bn_m[l], bn_v[l], y_nhwc);

    int tw1 = 9 * CO_ * C_;
    transform_w<<<(tw1 + 255) / 256, 256, 0, stream>>>(conv_w[l], wt_s, tw1, CO_);
    if (l == 0)
      conv3x3_mfma<__bf16><<<dim3(8, 2, 16), 256, 0, stream>>>(
          y_nhwc, wt_s, conv_b[l], CO_, 0, outbuf_bf, nullptr, nullptr, nullptr, nullptr);
    else
      conv3x3_mfma<float><<<dim3(8, 2, 16), 256, 0, stream>>>(
          y_nhwc, wt_s, conv_b[l], CO_, 0, outbuf_f, resid, nullptr, nullptr, nullptr);

    int tw2 = 9 * QKVC * C_;
    transform_w<<<(tw2 + 255) / 256, 256, 0, stream>>>(qkv_w[l], wt_s, tw2, QKVC);
    conv3x3_mfma<float><<<dim3(8, 11, 16), 256, 0, stream>>>(
        y_nhwc, wt_s, qkv_b[l], QKVC, 1, nullptr, nullptr, qt, kt2, vt);

    attn_kernel<<<dim3(64, NH_, 16), 256, 0, stream>>>(
        qt, kt2, vt, rel_w[l], rel_h[l], attn_c);

    if (l == 0)
      proj1x1<__bf16><<<dim3(4, 16), 256, 0, stream>>>(
          attn_c, attn_w[l], attn_b[l], outbuf_bf, nullptr);
    else
      proj1x1<float><<<dim3(4, 16), 256, 0, stream>>>(
          attn_c, attn_w[l], attn_b[l], outbuf_f, resid);
  }
}